// Round 22
// baseline (57.933 us; speedup 1.0000x reference)
//
#include <hip/hip_runtime.h>
#include <stdint.h>
#include <float.h>

// Chamfer distance, B=4, N=M=4096, 3D fp32.
// Outputs (flat, float32): [0] loss, [1..16384] idx12 (float), [16385..32768] idx21.
//
// SEMANTIC CONTRACT (validated R14-R21, absmax 0.0 — do not change):
//   d in f64: d = fma(dx,dx, fma(dy,dy, dz*dz)), dx = x - bx (f64-promoted f32)
//   pick = smallest index j with d_j <= fma(TOL_K(dir), a2 + b2_j, dmin)
//     (a2, b2_j in f64 from promoted f32 coords)
//   K12 = 0.6*2^-23, K21 = 0.   dmin = exact f64 min.
//   Prefilter (R16-proven 2x margin): survivor iff
//     d32 <= fma(2e-7, a2f+b2f_j, me), me = m*(1+2e-6), m = global f32 min.
//   Split skip (R18-validated): skip iff splitmin > (me + 7e-7*a2f)*(1+4e-6).
//
// R22: node-count collapse (3 -> 2). min32 = R20's known-good LDS version
// (R21's scalar-load variant pathological under PMC: same-address s_load storm).
// cd_loss fused into cd_select via last-block-done (threadfence + atomic
// counter, counter zeroed by min32 upstream in-stream; loss reduction code
// verbatim = deterministic fixed order). Tests the fixed-overhead hypothesis:
// kernel-sum ~19us vs dur_us pinned ~50us across R18-R21.

constexpr int B_ = 4;
constexpr int N_ = 4096;
constexpr int PTS = 256;
constexpr int PPT = 8;
constexpr int TILES = N_ / (PTS * PPT);  // 2
constexpr int JSPLIT = 32;
constexpr int CHUNK = N_ / JSPLIT;       // 128
constexpr double EPS32 = 1.1920928955078125e-7;  // 2^-23
constexpr double TOL_K12 = 0.6 * EPS32;
constexpr double TOL_K21 = 0.0;
constexpr double BETA_ = 1.0;
constexpr double GAMMA_ = 1.0;
constexpr double DELTA_ = 0.0;

// grid: (TILES*B_*2, JSPLIT)
__global__ __launch_bounds__(256) void cd_min32(
        const float* __restrict__ xyz1, const float* __restrict__ xyz2,
        unsigned int* __restrict__ splitmin, unsigned int* __restrict__ done) {
    if (blockIdx.x == 0 && blockIdx.y == 0 && threadIdx.x == 0)
        *done = 0u;                      // reset last-block counter each call

    const int tile  = blockIdx.x % TILES;
    const int b     = (blockIdx.x / TILES) % B_;
    const int dir   = blockIdx.x / (TILES * B_);
    const int split = blockIdx.y;
    const float* A  = dir ? xyz2 : xyz1;
    const float* Bc = dir ? xyz1 : xyz2;

    __shared__ float4 s[CHUNK];          // 2 KiB
    const float* bbase = Bc + ((size_t)b * N_ + (size_t)split * CHUNK) * 3;
    if (threadIdx.x < CHUNK) {
        int j = threadIdx.x;
        s[j] = make_float4(bbase[3 * j], bbase[3 * j + 1], bbase[3 * j + 2], 0.f);
    }
    __syncthreads();

    float px[PPT], py[PPT], pz[PPT], mn[PPT];
    #pragma unroll
    for (int pi = 0; pi < PPT; ++pi) {
        const int p = tile * (PTS * PPT) + pi * PTS + threadIdx.x;
        const float* ap = A + ((size_t)b * N_ + p) * 3;
        px[pi] = ap[0]; py[pi] = ap[1]; pz[pi] = ap[2];
        mn[pi] = FLT_MAX;
    }

    #pragma unroll 4
    for (int j = 0; j < CHUNK; ++j) {
        float4 bv = s[j];
        #pragma unroll
        for (int pi = 0; pi < PPT; ++pi) {
            float dx = px[pi] - bv.x, dy = py[pi] - bv.y, dz = pz[pi] - bv.z;
            mn[pi] = fminf(mn[pi],
                           __fmaf_rn(dx, dx, __fmaf_rn(dy, dy, dz * dz)));
        }
    }

    const size_t ob = (size_t)dir * B_ + b;
    const size_t sm = (ob * JSPLIT + split) * N_;
    #pragma unroll
    for (int pi = 0; pi < PPT; ++pi) {
        const int p = tile * (PTS * PPT) + pi * PTS + threadIdx.x;
        splitmin[sm + p] = __float_as_uint(mn[pi]);   // block-owned store
    }
}

// grid: 2*B_*64 = 512 blocks; blockIdx.x = ((dir*B_+b)<<6)|c64 ; 64 pts/block
__global__ __launch_bounds__(256) void cd_select(
        const float* __restrict__ xyz1, const float* __restrict__ xyz2,
        const unsigned int* __restrict__ splitmin,
        double2* __restrict__ partials, unsigned int* __restrict__ done,
        float* __restrict__ out) {
    const int c64 = blockIdx.x & 63;
    const int b   = (blockIdx.x >> 6) & (B_ - 1);
    const int dir = blockIdx.x >> 8;
    const int p0  = c64 * 64;
    const float* A  = dir ? xyz2 : xyz1;
    const float* Bc = dir ? xyz1 : xyz2;
    const double tolk = dir ? TOL_K21 : TOL_K12;
    const size_t ob = (size_t)dir * B_ + b;

    __shared__ unsigned int ltab[64][33];        // padded: conflict-free
    __shared__ unsigned short queue[2048];       // worst case 64*32
    __shared__ unsigned long long dbits[64];
    __shared__ unsigned int pickS[64];
    __shared__ float pc[64][5];                  // x,y,z,a2f,me
    __shared__ unsigned int cnt_total;
    __shared__ int is_last;

    // phase 1: coalesced panel load, transposed store
    #pragma unroll
    for (int k = 0; k < 8; ++k) {
        int idx = threadIdx.x + 256 * k;
        int row = idx >> 6, col = idx & 63;
        ltab[col][row] = splitmin[(ob * JSPLIT + row) * N_ + p0 + col];
    }
    __syncthreads();

    const int t = threadIdx.x;
    // phase 2 (wave 0): per-point m, mask, queue build
    if (t < 64) {
        const int p = p0 + t;
        const float* ap = A + ((size_t)b * N_ + p) * 3;
        const float x = ap[0], y = ap[1], z = ap[2];
        const float a2f = x * x + y * y + z * z;

        float m = FLT_MAX;
        #pragma unroll
        for (int s = 0; s < JSPLIT; ++s)
            m = fminf(m, __uint_as_float(ltab[t][s]));

        const float me = __fmaf_rn(2e-6f, m, m);
        const float skipthr = (me + 7e-7f * a2f) * (1.0f + 4e-6f);

        unsigned int mask = 0;
        #pragma unroll
        for (int s = 0; s < JSPLIT; ++s)
            if (__uint_as_float(ltab[t][s]) <= skipthr) mask |= (1u << s);

        pc[t][0] = x; pc[t][1] = y; pc[t][2] = z; pc[t][3] = a2f; pc[t][4] = me;
        dbits[t] = ~0ULL;
        pickS[t] = 0xFFFFFFFFu;

        unsigned int cnt = (unsigned int)__popc(mask);
        unsigned int pre = cnt;                   // inclusive prefix over 64 lanes
        #pragma unroll
        for (int off = 1; off < 64; off <<= 1) {
            unsigned int o = (unsigned int)__shfl_up((int)pre, off);
            if (t >= off) pre += o;
        }
        unsigned int w = pre - cnt;
        while (mask) {
            int s = __ffs(mask) - 1; mask &= mask - 1;
            queue[w++] = (unsigned short)((t << 5) | s);
        }
        if (t == 63) cnt_total = pre;
    }
    __syncthreads();

    const int wv = t >> 6, lane = t & 63;
    const float* bb = Bc + (size_t)b * N_ * 3;
    const unsigned int ctot = cnt_total;

    // phase 3 pass 1: f64 dmin over prefilter survivors (queue entries)
    for (unsigned int e = wv; e < ctot; e += 4) {
        unsigned int q = queue[e];
        int i = q >> 5, s = q & 31;
        const float x = pc[i][0], y = pc[i][1], z = pc[i][2];
        const float a2f = pc[i][3], me = pc[i][4];
        const double xd = (double)x, yd = (double)y, zd = (double)z;

        double dmin = 1.0e300;
        int j = s * CHUNK + lane;
        #pragma unroll
        for (int k = 0; k < 2; ++k, j += 64) {
            float bx = bb[3 * j], by = bb[3 * j + 1], bz = bb[3 * j + 2];
            float dx = x - bx, dy = y - by, dz = z - bz;
            float d32 = __fmaf_rn(dx, dx, __fmaf_rn(dy, dy, dz * dz));
            float thr = __fmaf_rn(2e-7f, a2f + (bx * bx + by * by + bz * bz), me);
            if (d32 <= thr) {
                double ddx = xd - (double)bx, ddy = yd - (double)by,
                       ddz = zd - (double)bz;
                dmin = fmin(dmin, fma(ddx, ddx, fma(ddy, ddy, ddz * ddz)));
            }
        }
        #pragma unroll
        for (int off = 1; off < 64; off <<= 1)
            dmin = fmin(dmin, __shfl_xor(dmin, off));
        if (lane == 0)
            atomicMin(&dbits[i], (unsigned long long)__double_as_longlong(dmin));
    }
    __syncthreads();

    // phase 3 pass 2: contract pick
    for (unsigned int e = wv; e < ctot; e += 4) {
        unsigned int q = queue[e];
        int i = q >> 5, s = q & 31;
        const float x = pc[i][0], y = pc[i][1], z = pc[i][2];
        const float a2f = pc[i][3], me = pc[i][4];
        const double xd = (double)x, yd = (double)y, zd = (double)z;
        const double a2 = xd * xd + yd * yd + zd * zd;
        const double dminF = __longlong_as_double((long long)dbits[i]);

        unsigned int pick = 0xFFFFFFFFu;
        int j = s * CHUNK + lane;
        #pragma unroll
        for (int k = 0; k < 2; ++k, j += 64) {
            float bx = bb[3 * j], by = bb[3 * j + 1], bz = bb[3 * j + 2];
            float dx = x - bx, dy = y - by, dz = z - bz;
            float d32 = __fmaf_rn(dx, dx, __fmaf_rn(dy, dy, dz * dz));
            float thr = __fmaf_rn(2e-7f, a2f + (bx * bx + by * by + bz * bz), me);
            if (d32 <= thr) {
                double bxd = (double)bx, byd = (double)by, bzd = (double)bz;
                double ddx = xd - bxd, ddy = yd - byd, ddz = zd - bzd;
                double d64 = fma(ddx, ddx, fma(ddy, ddy, ddz * ddz));
                double M   = a2 + (bxd * bxd + byd * byd + bzd * bzd);
                if (d64 <= fma(tolk, M, dminF))
                    pick = (pick < (unsigned int)j) ? pick : (unsigned int)j;
            }
        }
        #pragma unroll
        for (int off = 1; off < 64; off <<= 1) {
            unsigned int o2 = (unsigned int)__shfl_xor((int)pick, off);
            pick = (o2 < pick) ? o2 : pick;
        }
        if (lane == 0) atomicMin(&pickS[i], pick);
    }
    __syncthreads();

    // phase 4 (wave 0): writeback + block loss partial (fixed butterfly order)
    if (t < 64) {
        const size_t obase = (dir == 0) ? (1 + (size_t)b * N_)
                                        : (1 + (size_t)B_ * N_ + (size_t)b * N_);
        out[obase + p0 + t] = (float)pickS[t];

        double dm = __longlong_as_double((long long)dbits[t]);
        double sum = dm, mx = dm;
        #pragma unroll
        for (int off = 1; off < 64; off <<= 1) {
            sum += __shfl_xor(sum, off);
            mx = fmax(mx, __shfl_xor(mx, off));
        }
        if (t == 0) partials[blockIdx.x] = make_double2(sum, mx);
    }

    // phase 5: last-block-done -> fixed-order loss (verbatim cd_loss body)
    if (t == 0) {
        __threadfence();                              // release partials store
        unsigned int old = atomicAdd(done, 1u);
        is_last = (old == gridDim.x - 1) ? 1 : 0;
    }
    __syncthreads();
    if (is_last) {
        __threadfence();                              // acquire all partials
        if (t < 64) {
            double total = 0.0;
            for (int bb2 = 0; bb2 < B_; ++bb2) {
                double2 v0 = partials[((0 * B_ + bb2) << 6) | t];
                double s12 = v0.x, m12 = v0.y;
                double2 v1 = partials[((1 * B_ + bb2) << 6) | t];
                double s21 = v1.x;
                #pragma unroll
                for (int off = 1; off < 64; off <<= 1) {
                    s12 += __shfl_xor(s12, off);
                    m12 = fmax(m12, __shfl_xor(m12, off));
                    s21 += __shfl_xor(s21, off);
                }
                if (t == 0)
                    total += s12 / (double)N_ + BETA_ * m12
                           + (GAMMA_ + DELTA_ * (double)N_) * (s21 / (double)N_);
            }
            if (t == 0) out[0] = (float)(total / (double)B_);
        }
    }
}

extern "C" void kernel_launch(void* const* d_in, const int* in_sizes, int n_in,
                              void* d_out, int out_size, void* d_ws, size_t ws_size,
                              hipStream_t stream) {
    const float* xyz1 = (const float*)d_in[0];
    const float* xyz2 = (const float*)d_in[1];
    float* out = (float*)d_out;

    double2* partials = (double2*)d_ws;                        // 512 double2
    unsigned int* done = (unsigned int*)(partials + 512);      // 1 u32
    unsigned int* splitmin = done + 64;                        // NP*JSPLIT (4 MiB)

    dim3 grid(TILES * B_ * 2, JSPLIT);
    cd_min32<<<grid, PTS, 0, stream>>>(xyz1, xyz2, splitmin, done);

    cd_select<<<2 * B_ * 64, 256, 0, stream>>>(xyz1, xyz2, splitmin,
                                               partials, done, out);
}

// Round 23
// 48.499 us; speedup vs baseline: 1.1945x; 1.1945x over previous
//
#include <hip/hip_runtime.h>
#include <stdint.h>
#include <float.h>

// Chamfer distance, B=4, N=M=4096, 3D fp32.
// Outputs (flat, float32): [0] loss, [1..16384] idx12 (float), [16385..32768] idx21.
//
// SEMANTIC CONTRACT (validated R14-R22, absmax 0.0 — do not change):
//   d in f64: d = fma(dx,dx, fma(dy,dy, dz*dz)), dx = x - bx (f64-promoted f32)
//   pick = smallest index j with d_j <= fma(TOL_K(dir), a2 + b2_j, dmin)
//     (a2, b2_j in f64 from promoted f32 coords)
//   K12 = 0.6*2^-23, K21 = 0.   dmin = exact f64 min.
//   Prefilter (R16-proven 2x margin): survivor iff
//     d32 <= fma(2e-7, a2f+b2f_j, me), me = m*(1+2e-6), m = global f32 min.
//   Split skip (R18-validated): skip iff splitmin > (me + 7e-7*a2f)*(1+4e-6).
//
// R23: select parallelism fix. R22 profile finally exposed cd_select = 40us
// (15% occ: 512 blocks, wave-0-serialized phases). New select: one WAVE per
// point (8192 blocks x 4 waves = 32K waves), block cooperatively loads its
// 4-point x 32-split panel into LDS (kills R18's 16KB-strided gather, one
// barrier), then each wave runs R18's select verbatim. min32 = R20/R22
// verbatim; finalize/loss = R18 verbatim. Fusion reverted (cost ~8us).

constexpr int B_ = 4;
constexpr int N_ = 4096;
constexpr int PTS = 256;
constexpr int PPT = 8;
constexpr int TILES = N_ / (PTS * PPT);  // 2
constexpr int JSPLIT = 32;
constexpr int CHUNK = N_ / JSPLIT;       // 128
constexpr double EPS32 = 1.1920928955078125e-7;  // 2^-23
constexpr double TOL_K12 = 0.6 * EPS32;
constexpr double TOL_K21 = 0.0;
constexpr double BETA_ = 1.0;
constexpr double GAMMA_ = 1.0;
constexpr double DELTA_ = 0.0;

// grid: (TILES*B_*2, JSPLIT)
__global__ __launch_bounds__(256) void cd_min32(
        const float* __restrict__ xyz1, const float* __restrict__ xyz2,
        unsigned int* __restrict__ splitmin) {
    const int tile  = blockIdx.x % TILES;
    const int b     = (blockIdx.x / TILES) % B_;
    const int dir   = blockIdx.x / (TILES * B_);
    const int split = blockIdx.y;
    const float* A  = dir ? xyz2 : xyz1;
    const float* Bc = dir ? xyz1 : xyz2;

    __shared__ float4 s[CHUNK];          // 2 KiB
    const float* bbase = Bc + ((size_t)b * N_ + (size_t)split * CHUNK) * 3;
    if (threadIdx.x < CHUNK) {
        int j = threadIdx.x;
        s[j] = make_float4(bbase[3 * j], bbase[3 * j + 1], bbase[3 * j + 2], 0.f);
    }
    __syncthreads();

    float px[PPT], py[PPT], pz[PPT], mn[PPT];
    #pragma unroll
    for (int pi = 0; pi < PPT; ++pi) {
        const int p = tile * (PTS * PPT) + pi * PTS + threadIdx.x;
        const float* ap = A + ((size_t)b * N_ + p) * 3;
        px[pi] = ap[0]; py[pi] = ap[1]; pz[pi] = ap[2];
        mn[pi] = FLT_MAX;
    }

    #pragma unroll 4
    for (int j = 0; j < CHUNK; ++j) {
        float4 bv = s[j];
        #pragma unroll
        for (int pi = 0; pi < PPT; ++pi) {
            float dx = px[pi] - bv.x, dy = py[pi] - bv.y, dz = pz[pi] - bv.z;
            mn[pi] = fminf(mn[pi],
                           __fmaf_rn(dx, dx, __fmaf_rn(dy, dy, dz * dz)));
        }
    }

    const size_t ob = (size_t)dir * B_ + b;
    const size_t sm = (ob * JSPLIT + split) * N_;
    #pragma unroll
    for (int pi = 0; pi < PPT; ++pi) {
        const int p = tile * (PTS * PPT) + pi * PTS + threadIdx.x;
        splitmin[sm + p] = __float_as_uint(mn[pi]);   // block-owned store
    }
}

// one wave per point; grid: (2*B_*N_)/4 = 8192 blocks of 256 (4 waves/block).
// Block's 4 points share (dir,b) since N_ % 4 == 0 and blocks align.
__global__ __launch_bounds__(256) void cd_select(
        const float* __restrict__ xyz1, const float* __restrict__ xyz2,
        const unsigned int* __restrict__ splitmin,
        double* __restrict__ dminArr, float* __restrict__ out) {
    const int W0   = blockIdx.x * 4;                 // first point id of block
    const int dir  = W0 / (B_ * N_);
    const int b    = (W0 / N_) % B_;
    const int p0   = W0 % N_;
    const float* A  = dir ? xyz2 : xyz1;
    const float* Bc = dir ? xyz1 : xyz2;
    const double tolk = dir ? TOL_K21 : TOL_K12;
    const size_t ob = (size_t)dir * B_ + b;

    __shared__ unsigned int lt[4][32];               // 512 B panel

    // phase 1: cooperative panel load (replaces per-wave strided gather)
    if (threadIdx.x < 128) {
        const int s  = threadIdx.x >> 2;
        const int pi = threadIdx.x & 3;
        lt[pi][s] = splitmin[(ob * JSPLIT + s) * N_ + p0 + pi];
    }
    __syncthreads();

    const int wv   = threadIdx.x >> 6;               // wave -> point p0+wv
    const int lane = threadIdx.x & 63;
    const int p    = p0 + wv;
    const int W    = W0 + wv;

    const float* ap = A + ((size_t)b * N_ + p) * 3;
    const float x = ap[0], y = ap[1], z = ap[2];
    const float a2f = x * x + y * y + z * z;

    // m = min over 32 per-split minima (bit-identical to global f32 min)
    const int l32 = lane & 31;
    const float sv = __uint_as_float(lt[wv][l32]);
    float m = sv;
    #pragma unroll
    for (int off = 1; off < 32; off <<= 1)
        m = fminf(m, __shfl_xor(m, off));

    const float me = __fmaf_rn(2e-6f, m, m);         // m*(1+2e-6)
    const float skipthr = (me + 7e-7f * a2f) * (1.0f + 4e-6f);
    unsigned int mask = (unsigned int)__ballot(lane < 32 && sv <= skipthr);

    const float* bb = Bc + (size_t)b * N_ * 3;
    const double xd = (double)x, yd = (double)y, zd = (double)z;
    const double a2 = xd * xd + yd * yd + zd * zd;

    // pass 1: f64 dmin over prefilter survivors (true argmin provably among them)
    double dmin = 1.0e300;
    unsigned int mk = mask;
    while (mk) {
        int s = __ffs(mk) - 1; mk &= mk - 1;
        int j = s * CHUNK + lane;
        #pragma unroll
        for (int k = 0; k < 2; ++k, j += 64) {
            float bx = bb[3 * j], by = bb[3 * j + 1], bz = bb[3 * j + 2];
            float dx = x - bx, dy = y - by, dz = z - bz;
            float d32 = __fmaf_rn(dx, dx, __fmaf_rn(dy, dy, dz * dz));
            float thr = __fmaf_rn(2e-7f, a2f + (bx * bx + by * by + bz * bz), me);
            if (d32 <= thr) {
                double ddx = xd - (double)bx, ddy = yd - (double)by,
                       ddz = zd - (double)bz;
                dmin = fmin(dmin, fma(ddx, ddx, fma(ddy, ddy, ddz * ddz)));
            }
        }
    }
    #pragma unroll
    for (int off = 1; off < 64; off <<= 1)
        dmin = fmin(dmin, __shfl_xor(dmin, off));

    // pass 2: smallest index with d64 <= fma(tolk, M64, dmin)  [contract]
    unsigned int pick = 0xFFFFFFFFu;
    mk = mask;
    while (mk) {
        int s = __ffs(mk) - 1; mk &= mk - 1;
        int j = s * CHUNK + lane;
        #pragma unroll
        for (int k = 0; k < 2; ++k, j += 64) {
            float bx = bb[3 * j], by = bb[3 * j + 1], bz = bb[3 * j + 2];
            float dx = x - bx, dy = y - by, dz = z - bz;
            float d32 = __fmaf_rn(dx, dx, __fmaf_rn(dy, dy, dz * dz));
            float thr = __fmaf_rn(2e-7f, a2f + (bx * bx + by * by + bz * bz), me);
            if (d32 <= thr) {
                double bxd = (double)bx, byd = (double)by, bzd = (double)bz;
                double ddx = xd - bxd, ddy = yd - byd, ddz = zd - bzd;
                double d64 = fma(ddx, ddx, fma(ddy, ddy, ddz * ddz));
                double M   = a2 + (bxd * bxd + byd * byd + bzd * bzd);
                if (d64 <= fma(tolk, M, dmin))
                    pick = (pick < (unsigned int)j) ? pick : (unsigned int)j;
            }
        }
    }
    #pragma unroll
    for (int off = 1; off < 64; off <<= 1) {
        unsigned int o2 = (unsigned int)__shfl_xor((int)pick, off);
        pick = (o2 < pick) ? o2 : pick;
    }

    if (lane == 0) {
        dminArr[W] = dmin;
        const size_t obase = (dir == 0) ? (1 + (size_t)b * N_)
                                        : (1 + (size_t)B_ * N_ + (size_t)b * N_);
        out[obase + p] = (float)pick;
    }
}

__global__ __launch_bounds__(256) void cd_finalize(
        const double* __restrict__ dminArr, float* __restrict__ out,
        double* __restrict__ loss_part) {
    const int b = blockIdx.x;
    const int t = threadIdx.x;

    double sum12 = 0.0, max12 = -1.0e300, sum21 = 0.0;
    for (int n = t; n < N_; n += 256) {
        double d12 = dminArr[(size_t)b * N_ + n];
        double d21 = dminArr[((size_t)B_ + b) * N_ + n];
        sum12 += d12;
        max12 = fmax(max12, d12);
        sum21 += d21;
    }
    __shared__ double s1[256], s2[256], s3[256];
    s1[t] = sum12; s2[t] = max12; s3[t] = sum21;
    __syncthreads();
    for (int off = 128; off > 0; off >>= 1) {
        if (t < off) {
            s1[t] += s1[t + off];
            s2[t]  = fmax(s2[t], s2[t + off]);
            s3[t] += s3[t + off];
        }
        __syncthreads();
    }
    if (t == 0) {
        loss_part[b] = s1[0] / (double)N_ + BETA_ * s2[0]
                     + (GAMMA_ + DELTA_ * (double)N_) * (s3[0] / (double)N_);
    }
}

__global__ void cd_loss(const double* __restrict__ loss_part,
                        float* __restrict__ out) {
    if (blockIdx.x == 0 && threadIdx.x == 0) {
        double s = 0.0;
        for (int b = 0; b < B_; ++b) s += loss_part[b];  // fixed order
        out[0] = (float)(s / (double)B_);
    }
}

extern "C" void kernel_launch(void* const* d_in, const int* in_sizes, int n_in,
                              void* d_out, int out_size, void* d_ws, size_t ws_size,
                              hipStream_t stream) {
    const float* xyz1 = (const float*)d_in[0];
    const float* xyz2 = (const float*)d_in[1];
    float* out = (float*)d_out;

    const size_t NP = (size_t)2 * B_ * N_;       // 32768 points
    double* dminArr   = (double*)d_ws;           // NP doubles
    double* loss_part = dminArr + NP;            // B_ doubles
    unsigned int* splitmin = (unsigned int*)(loss_part + B_);  // NP*JSPLIT (4 MiB)

    dim3 grid(TILES * B_ * 2, JSPLIT);
    cd_min32<<<grid, PTS, 0, stream>>>(xyz1, xyz2, splitmin);

    cd_select<<<(int)(NP / 4), 256, 0, stream>>>(xyz1, xyz2, splitmin,
                                                 dminArr, out);

    cd_finalize<<<B_, 256, 0, stream>>>(dminArr, out, loss_part);
    cd_loss<<<1, 64, 0, stream>>>(loss_part, out);
}

// Round 24
// 48.478 us; speedup vs baseline: 1.1950x; 1.0004x over previous
//
#include <hip/hip_runtime.h>
#include <stdint.h>
#include <float.h>

// Chamfer distance, B=4, N=M=4096, 3D fp32.
// Outputs (flat, float32): [0] loss, [1..16384] idx12 (float), [16385..32768] idx21.
//
// SEMANTIC CONTRACT (validated R14-R23, absmax 0.0 — do not change):
//   d in f64: d = fma(dx,dx, fma(dy,dy, dz*dz)), dx = x - bx (f64-promoted f32)
//   pick = smallest index j with d_j <= fma(TOL_K(dir), a2 + b2_j, dmin)
//     (a2, b2_j in f64 from promoted f32 coords)
//   K12 = 0.6*2^-23, K21 = 0.   dmin = exact f64 min.
//   Prefilter (R16-proven 2x margin, conservative under any f32 rounding):
//     survivor iff d32 <= fma(2e-7, a2f+b2f_j, me), me = m*(1+2e-6).
//   Split skip (R18-validated): skip iff splitmin > (me + 7e-7*a2f)*(1+4e-6).
//
// R24: select was latency-bound on 12B-stride scalar target loads (3 dword
// loads/candidate, ~36 line-transactions, serial ~250cyc rounds => ~2600
// cyc/wave). min32 now emits a float4-packed cloud b4[ob][j]={x,y,z,b2f}
// (512KB, from its staged LDS tile); select reads one dwordx4 per candidate
// and takes b2f from .w (prefilter only; margin covers rounding). Exact f64
// contract math unchanged (recomputed from .xyz). Rest = R23 verbatim.

constexpr int B_ = 4;
constexpr int N_ = 4096;
constexpr int PTS = 256;
constexpr int PPT = 8;
constexpr int TILES = N_ / (PTS * PPT);  // 2
constexpr int JSPLIT = 32;
constexpr int CHUNK = N_ / JSPLIT;       // 128
constexpr double EPS32 = 1.1920928955078125e-7;  // 2^-23
constexpr double TOL_K12 = 0.6 * EPS32;
constexpr double TOL_K21 = 0.0;
constexpr double BETA_ = 1.0;
constexpr double GAMMA_ = 1.0;
constexpr double DELTA_ = 0.0;

// grid: (TILES*B_*2, JSPLIT)
__global__ __launch_bounds__(256) void cd_min32(
        const float* __restrict__ xyz1, const float* __restrict__ xyz2,
        unsigned int* __restrict__ splitmin, float4* __restrict__ b4) {
    const int tile  = blockIdx.x % TILES;
    const int b     = (blockIdx.x / TILES) % B_;
    const int dir   = blockIdx.x / (TILES * B_);
    const int split = blockIdx.y;
    const float* A  = dir ? xyz2 : xyz1;
    const float* Bc = dir ? xyz1 : xyz2;
    const size_t ob = (size_t)dir * B_ + b;

    __shared__ float4 s[CHUNK];          // 2 KiB
    const float* bbase = Bc + ((size_t)b * N_ + (size_t)split * CHUNK) * 3;
    if (threadIdx.x < CHUNK) {
        int j = threadIdx.x;
        float bx = bbase[3 * j], by = bbase[3 * j + 1], bz = bbase[3 * j + 2];
        float b2 = bx * bx + by * by + bz * bz;   // prefilter-only (margin ok)
        float4 v = make_float4(bx, by, bz, b2);
        s[j] = v;
        if (tile == 0)                    // one writer per (dir,b,split)
            b4[ob * N_ + (size_t)split * CHUNK + j] = v;
    }
    __syncthreads();

    float px[PPT], py[PPT], pz[PPT], mn[PPT];
    #pragma unroll
    for (int pi = 0; pi < PPT; ++pi) {
        const int p = tile * (PTS * PPT) + pi * PTS + threadIdx.x;
        const float* ap = A + ((size_t)b * N_ + p) * 3;
        px[pi] = ap[0]; py[pi] = ap[1]; pz[pi] = ap[2];
        mn[pi] = FLT_MAX;
    }

    #pragma unroll 4
    for (int j = 0; j < CHUNK; ++j) {
        float4 bv = s[j];
        #pragma unroll
        for (int pi = 0; pi < PPT; ++pi) {
            float dx = px[pi] - bv.x, dy = py[pi] - bv.y, dz = pz[pi] - bv.z;
            mn[pi] = fminf(mn[pi],
                           __fmaf_rn(dx, dx, __fmaf_rn(dy, dy, dz * dz)));
        }
    }

    const size_t sm = (ob * JSPLIT + split) * N_;
    #pragma unroll
    for (int pi = 0; pi < PPT; ++pi) {
        const int p = tile * (PTS * PPT) + pi * PTS + threadIdx.x;
        splitmin[sm + p] = __float_as_uint(mn[pi]);   // block-owned store
    }
}

// one wave per point; grid: (2*B_*N_)/4 = 8192 blocks of 256 (4 waves/block)
__global__ __launch_bounds__(256) void cd_select(
        const float* __restrict__ xyz1, const float* __restrict__ xyz2,
        const unsigned int* __restrict__ splitmin, const float4* __restrict__ b4,
        double* __restrict__ dminArr, float* __restrict__ out) {
    const int W0   = blockIdx.x * 4;                 // first point id of block
    const int dir  = W0 / (B_ * N_);
    const int b    = (W0 / N_) % B_;
    const int p0   = W0 % N_;
    const float* A  = dir ? xyz2 : xyz1;
    const double tolk = dir ? TOL_K21 : TOL_K12;
    const size_t ob = (size_t)dir * B_ + b;
    const float4* bb4 = b4 + ob * N_;

    __shared__ unsigned int lt[4][32];               // 512 B panel

    // phase 1: cooperative panel load
    if (threadIdx.x < 128) {
        const int s  = threadIdx.x >> 2;
        const int pi = threadIdx.x & 3;
        lt[pi][s] = splitmin[(ob * JSPLIT + s) * N_ + p0 + pi];
    }
    __syncthreads();

    const int wv   = threadIdx.x >> 6;               // wave -> point p0+wv
    const int lane = threadIdx.x & 63;
    const int p    = p0 + wv;
    const int W    = W0 + wv;

    const float* ap = A + ((size_t)b * N_ + p) * 3;
    const float x = ap[0], y = ap[1], z = ap[2];
    const float a2f = x * x + y * y + z * z;

    // m = min over 32 per-split minima (== global f32 min, bit-identical)
    const int l32 = lane & 31;
    const float sv = __uint_as_float(lt[wv][l32]);
    float m = sv;
    #pragma unroll
    for (int off = 1; off < 32; off <<= 1)
        m = fminf(m, __shfl_xor(m, off));

    const float me = __fmaf_rn(2e-6f, m, m);         // m*(1+2e-6)
    const float skipthr = (me + 7e-7f * a2f) * (1.0f + 4e-6f);
    unsigned int mask = (unsigned int)__ballot(lane < 32 && sv <= skipthr);

    const double xd = (double)x, yd = (double)y, zd = (double)z;
    const double a2 = xd * xd + yd * yd + zd * zd;

    // pass 1: f64 dmin over prefilter survivors (true argmin provably among them)
    double dmin = 1.0e300;
    unsigned int mk = mask;
    while (mk) {
        int s = __ffs(mk) - 1; mk &= mk - 1;
        int j0 = s * CHUNK + lane;
        float4 bv0 = bb4[j0];
        float4 bv1 = bb4[j0 + 64];
        #pragma unroll
        for (int k = 0; k < 2; ++k) {
            float4 bv = k ? bv1 : bv0;
            float dx = x - bv.x, dy = y - bv.y, dz = z - bv.z;
            float d32 = __fmaf_rn(dx, dx, __fmaf_rn(dy, dy, dz * dz));
            float thr = __fmaf_rn(2e-7f, a2f + bv.w, me);
            if (d32 <= thr) {
                double ddx = xd - (double)bv.x, ddy = yd - (double)bv.y,
                       ddz = zd - (double)bv.z;
                dmin = fmin(dmin, fma(ddx, ddx, fma(ddy, ddy, ddz * ddz)));
            }
        }
    }
    #pragma unroll
    for (int off = 1; off < 64; off <<= 1)
        dmin = fmin(dmin, __shfl_xor(dmin, off));

    // pass 2: smallest index with d64 <= fma(tolk, M64, dmin)  [contract]
    unsigned int pick = 0xFFFFFFFFu;
    mk = mask;
    while (mk) {
        int s = __ffs(mk) - 1; mk &= mk - 1;
        int j0 = s * CHUNK + lane;
        float4 bv0 = bb4[j0];
        float4 bv1 = bb4[j0 + 64];
        #pragma unroll
        for (int k = 0; k < 2; ++k) {
            float4 bv = k ? bv1 : bv0;
            int j = j0 + k * 64;
            float dx = x - bv.x, dy = y - bv.y, dz = z - bv.z;
            float d32 = __fmaf_rn(dx, dx, __fmaf_rn(dy, dy, dz * dz));
            float thr = __fmaf_rn(2e-7f, a2f + bv.w, me);
            if (d32 <= thr) {
                double bxd = (double)bv.x, byd = (double)bv.y, bzd = (double)bv.z;
                double ddx = xd - bxd, ddy = yd - byd, ddz = zd - bzd;
                double d64 = fma(ddx, ddx, fma(ddy, ddy, ddz * ddz));
                double M   = a2 + (bxd * bxd + byd * byd + bzd * bzd);
                if (d64 <= fma(tolk, M, dmin))
                    pick = (pick < (unsigned int)j) ? pick : (unsigned int)j;
            }
        }
    }
    #pragma unroll
    for (int off = 1; off < 64; off <<= 1) {
        unsigned int o2 = (unsigned int)__shfl_xor((int)pick, off);
        pick = (o2 < pick) ? o2 : pick;
    }

    if (lane == 0) {
        dminArr[W] = dmin;
        const size_t obase = (dir == 0) ? (1 + (size_t)b * N_)
                                        : (1 + (size_t)B_ * N_ + (size_t)b * N_);
        out[obase + p] = (float)pick;
    }
}

__global__ __launch_bounds__(256) void cd_finalize(
        const double* __restrict__ dminArr, float* __restrict__ out,
        double* __restrict__ loss_part) {
    const int b = blockIdx.x;
    const int t = threadIdx.x;

    double sum12 = 0.0, max12 = -1.0e300, sum21 = 0.0;
    for (int n = t; n < N_; n += 256) {
        double d12 = dminArr[(size_t)b * N_ + n];
        double d21 = dminArr[((size_t)B_ + b) * N_ + n];
        sum12 += d12;
        max12 = fmax(max12, d12);
        sum21 += d21;
    }
    __shared__ double s1[256], s2[256], s3[256];
    s1[t] = sum12; s2[t] = max12; s3[t] = sum21;
    __syncthreads();
    for (int off = 128; off > 0; off >>= 1) {
        if (t < off) {
            s1[t] += s1[t + off];
            s2[t]  = fmax(s2[t], s2[t + off]);
            s3[t] += s3[t + off];
        }
        __syncthreads();
    }
    if (t == 0) {
        loss_part[b] = s1[0] / (double)N_ + BETA_ * s2[0]
                     + (GAMMA_ + DELTA_ * (double)N_) * (s3[0] / (double)N_);
    }
}

__global__ void cd_loss(const double* __restrict__ loss_part,
                        float* __restrict__ out) {
    if (blockIdx.x == 0 && threadIdx.x == 0) {
        double s = 0.0;
        for (int b = 0; b < B_; ++b) s += loss_part[b];  // fixed order
        out[0] = (float)(s / (double)B_);
    }
}

extern "C" void kernel_launch(void* const* d_in, const int* in_sizes, int n_in,
                              void* d_out, int out_size, void* d_ws, size_t ws_size,
                              hipStream_t stream) {
    const float* xyz1 = (const float*)d_in[0];
    const float* xyz2 = (const float*)d_in[1];
    float* out = (float*)d_out;

    const size_t NP = (size_t)2 * B_ * N_;       // 32768 points
    double* dminArr   = (double*)d_ws;           // NP doubles
    double* loss_part = dminArr + NP;            // B_ doubles
    unsigned int* splitmin = (unsigned int*)(loss_part + B_);  // NP*JSPLIT (4 MiB)
    float4* b4 = (float4*)(splitmin + NP * JSPLIT);            // 2*B_*N_ float4 (512 KiB)

    dim3 grid(TILES * B_ * 2, JSPLIT);
    cd_min32<<<grid, PTS, 0, stream>>>(xyz1, xyz2, splitmin, b4);

    cd_select<<<(int)(NP / 4), 256, 0, stream>>>(xyz1, xyz2, splitmin, b4,
                                                 dminArr, out);

    cd_finalize<<<B_, 256, 0, stream>>>(dminArr, out, loss_part);
    cd_loss<<<1, 64, 0, stream>>>(loss_part, out);
}